// Round 8
// baseline (581.203 us; speedup 1.0000x reference)
//
#include <hip/hip_runtime.h>
#include <hip/hip_bf16.h>

// Problem constants
#define B_  4
#define N_  16
#define T_  2048
#define F_  512
#define NC_ 43
constexpr float LN_EPS = 1e-5f;

constexpr int EMB1_N = NC_ * F_;            // 22016 (fp32)
constexpr int WBOX_N = F_ * 4;              // 2048  (fp32)
constexpr int W2BF_N = F_ * F_;             // 262144 (bf16) native [f][c]
constexpr int WMT_N  = F_ * N_ * F_;        // 4194304 (bf16), wmT[f][k], k=n*F+c
constexpr int K_TOT  = N_ * F_;             // 8192

typedef __bf16 bf16x8_t __attribute__((ext_vector_type(8)));
typedef float  f32x4_t  __attribute__((ext_vector_type(4)));

__device__ __forceinline__ void gload16(const void* g, void* l) {
  __builtin_amdgcn_global_load_lds(
      (const __attribute__((address_space(1))) unsigned int*)g,
      (__attribute__((address_space(3))) unsigned int*)l, 16, 0, 0);
}

__device__ __forceinline__ short bf16s(float x) {
  return (short)__bfloat16_as_ushort(__float2bfloat16(x));
}
__device__ __forceinline__ float bf2f(short s) {
  return __uint_as_float(((unsigned)(unsigned short)s) << 16);
}

// ---------------------------------------------------------------------------
// K0a: emb1[k][f] = sum_c emb_table[k][c] * W1[f][c]
//      wbox[f][q] = sum_c W1[f][F+c] * W_lin[c][q]
//      w2bf[f][c] = bf16(W2[f][c])
// ---------------------------------------------------------------------------
__global__ __launch_bounds__(256) void precompute_small(
    const float* __restrict__ emb_table, const float* __restrict__ W1,
    const float* __restrict__ W_lin, const float* __restrict__ W2,
    float* __restrict__ emb1, float* __restrict__ wbox,
    __hip_bfloat16* __restrict__ w2bf)
{
  int idx = blockIdx.x * 256 + threadIdx.x;
  if (idx < EMB1_N) {
    int k = idx >> 9, f = idx & 511;
    const float4* et = (const float4*)&emb_table[k * F_];
    const float4* w1 = (const float4*)&W1[f * (2 * F_)];
    float s = 0.f;
    for (int c4 = 0; c4 < F_ / 4; ++c4) {
      float4 a = et[c4], b = w1[c4];
      s = fmaf(a.x, b.x, s); s = fmaf(a.y, b.y, s);
      s = fmaf(a.z, b.z, s); s = fmaf(a.w, b.w, s);
    }
    emb1[idx] = s;
  } else if (idx < EMB1_N + WBOX_N) {
    int t2 = idx - EMB1_N;
    int f = t2 >> 2, q = t2 & 3;
    const float4* w1 = (const float4*)&W1[f * (2 * F_) + F_];
    float s = 0.f;
    for (int c4 = 0; c4 < F_ / 4; ++c4) {
      float4 a = w1[c4];
      s = fmaf(a.x, W_lin[(c4 * 4 + 0) * 4 + q], s);
      s = fmaf(a.y, W_lin[(c4 * 4 + 1) * 4 + q], s);
      s = fmaf(a.z, W_lin[(c4 * 4 + 2) * 4 + q], s);
      s = fmaf(a.w, W_lin[(c4 * 4 + 3) * 4 + q], s);
    }
    wbox[t2] = s;
  } else if (idx < EMB1_N + WBOX_N + W2BF_N) {
    int t3 = idx - (EMB1_N + WBOX_N);
    w2bf[t3] = __float2bfloat16(W2[t3]);
  }
}

// ---------------------------------------------------------------------------
// K0b: wmT[f][k], k=n*F+c  <-  Wm[f][c][n].  One f per block; coalesced read
// into padded LDS tile (stride 517), coalesced bf16 write.  (r5, proven)
// ---------------------------------------------------------------------------
__global__ __launch_bounds__(256) void precompute_wmT(
    const float* __restrict__ Wm, __hip_bfloat16* __restrict__ wmT)
{
  __shared__ float tile[16 * 517];  // [n][c], 33 KB
  const int f = blockIdx.x;
  const float* src = Wm + (long long)f * 8192;   // [c][n]: idx = c*16+n
  for (int i = threadIdx.x; i < 8192; i += 256) {
    int c = i >> 4, n = i & 15;
    tile[n * 517 + c] = src[i];
  }
  __syncthreads();
  short* dst = (short*)wmT + (long long)f * 8192;  // [n][c]: o = n*512+c
  for (int i = threadIdx.x; i < 4096; i += 256) {
    int o = i << 1;
    int n = o >> 9, c = o & 511;
    short2 sv;
    sv.x = bf16s(tile[n * 517 + c]);
    sv.y = bf16s(tile[n * 517 + c + 1]);
    *(short2*)&dst[o] = sv;
  }
}

// ---------------------------------------------------------------------------
// k_h1g (r4 structure; bufA/bufB now bf16 in LDS, fp32 compute):
//   per pixel p=(b,t): node1 -> h1=relu(em@node1) -> g=em@h1 -> bf16
// LDS 67 KB -> 33.5 KB: 2 -> 4 blocks/CU (occupancy was the measured limiter:
// 22.9% occ, 40% VALUBusy, HBM 11%). Access pattern identical to r4 —
// wave-per-pixel (r5) and register-h1 (r6) both regressed via memory system.
// ---------------------------------------------------------------------------
__global__ __launch_bounds__(256) void k_h1g(
    const float* __restrict__ bbox, const int* __restrict__ cls,
    const float* __restrict__ edge, const float* __restrict__ emb1,
    const float* __restrict__ wbox, __hip_bfloat16* __restrict__ g)
{
  __shared__ float em_s[256];
  __shared__ __align__(16) short bufA[N_ * F_];   // node1, bf16
  __shared__ __align__(16) short bufB[N_ * F_];   // h1,    bf16
  __shared__ int   cls_s[N_];
  __shared__ float bb_s[N_ * 4];

  const int p = blockIdx.x;
  const int b = p >> 11;
  const int t = p & 2047;
  const int tid = threadIdx.x;

  {
    int i = tid >> 4, j = tid & 15;
    em_s[tid] = edge[(((b * N_ + i) * N_ + j) * T_) + t];
  }
  if (tid < N_) cls_s[tid] = cls[(b * N_ + tid) * T_ + t];
  if (tid < N_ * 4) {
    int j = tid >> 2, q = tid & 3;
    bb_s[tid] = bbox[(((b * N_ + j) * 4 + q) * T_) + t];
  }
  __syncthreads();

  // S1: node1 -> bufA (bf16); emb1 gather pattern identical to r4 (L2-hot)
  const float4* wb4 = (const float4*)wbox;
  for (int idx = tid; idx < N_ * F_; idx += 256) {
    int j = idx >> 9, f = idx & 511;
    float4 wb = wb4[f];
    float v = emb1[cls_s[j] * F_ + f];
    v = fmaf(bb_s[j * 4 + 0], wb.x, v);
    v = fmaf(bb_s[j * 4 + 1], wb.y, v);
    v = fmaf(bb_s[j * 4 + 2], wb.z, v);
    v = fmaf(bb_s[j * 4 + 3], wb.w, v);
    bufA[idx] = bf16s(v);
  }
  __syncthreads();

  const int w = tid >> 6, lane = tid & 63;
  float emr[4][16];
#pragma unroll
  for (int r = 0; r < 4; ++r)
#pragma unroll
    for (int j = 0; j < 16; ++j) emr[r][j] = em_s[(w * 4 + r) * 16 + j];

  // S2: h1 = relu(em @ node1) -> bufB (bf16)
#pragma unroll
  for (int chunk = 0; chunk < 2; ++chunk) {
    const int c0 = chunk * 256 + lane * 4;
    float4 a0 = {0, 0, 0, 0}, a1 = {0, 0, 0, 0}, a2 = {0, 0, 0, 0}, a3 = {0, 0, 0, 0};
#pragma unroll
    for (int j = 0; j < 16; ++j) {
      short4 sv = *(const short4*)&bufA[j * F_ + c0];
      float4 v;
      v.x = bf2f(sv.x); v.y = bf2f(sv.y); v.z = bf2f(sv.z); v.w = bf2f(sv.w);
      a0.x = fmaf(emr[0][j], v.x, a0.x); a0.y = fmaf(emr[0][j], v.y, a0.y);
      a0.z = fmaf(emr[0][j], v.z, a0.z); a0.w = fmaf(emr[0][j], v.w, a0.w);
      a1.x = fmaf(emr[1][j], v.x, a1.x); a1.y = fmaf(emr[1][j], v.y, a1.y);
      a1.z = fmaf(emr[1][j], v.z, a1.z); a1.w = fmaf(emr[1][j], v.w, a1.w);
      a2.x = fmaf(emr[2][j], v.x, a2.x); a2.y = fmaf(emr[2][j], v.y, a2.y);
      a2.z = fmaf(emr[2][j], v.z, a2.z); a2.w = fmaf(emr[2][j], v.w, a2.w);
      a3.x = fmaf(emr[3][j], v.x, a3.x); a3.y = fmaf(emr[3][j], v.y, a3.y);
      a3.z = fmaf(emr[3][j], v.z, a3.z); a3.w = fmaf(emr[3][j], v.w, a3.w);
    }
#pragma unroll
    for (int r = 0; r < 4; ++r) {
      float4 ar = (r == 0) ? a0 : (r == 1) ? a1 : (r == 2) ? a2 : a3;
      short4 sv;
      sv.x = bf16s(fmaxf(ar.x, 0.f));
      sv.y = bf16s(fmaxf(ar.y, 0.f));
      sv.z = bf16s(fmaxf(ar.z, 0.f));
      sv.w = bf16s(fmaxf(ar.w, 0.f));
      *(short4*)&bufB[(w * 4 + r) * F_ + c0] = sv;
    }
  }
  __syncthreads();

  // S3: g = em @ h1 -> global bf16
  long long base = (long long)p * (N_ * F_);
  short* gs = (short*)g;
#pragma unroll
  for (int chunk = 0; chunk < 2; ++chunk) {
    const int c0 = chunk * 256 + lane * 4;
    float4 a0 = {0, 0, 0, 0}, a1 = {0, 0, 0, 0}, a2 = {0, 0, 0, 0}, a3 = {0, 0, 0, 0};
#pragma unroll
    for (int j = 0; j < 16; ++j) {
      short4 sv = *(const short4*)&bufB[j * F_ + c0];
      float4 v;
      v.x = bf2f(sv.x); v.y = bf2f(sv.y); v.z = bf2f(sv.z); v.w = bf2f(sv.w);
      a0.x = fmaf(emr[0][j], v.x, a0.x); a0.y = fmaf(emr[0][j], v.y, a0.y);
      a0.z = fmaf(emr[0][j], v.z, a0.z); a0.w = fmaf(emr[0][j], v.w, a0.w);
      a1.x = fmaf(emr[1][j], v.x, a1.x); a1.y = fmaf(emr[1][j], v.y, a1.y);
      a1.z = fmaf(emr[1][j], v.z, a1.z); a1.w = fmaf(emr[1][j], v.w, a1.w);
      a2.x = fmaf(emr[2][j], v.x, a2.x); a2.y = fmaf(emr[2][j], v.y, a2.y);
      a2.z = fmaf(emr[2][j], v.z, a2.z); a2.w = fmaf(emr[2][j], v.w, a2.w);
      a3.x = fmaf(emr[3][j], v.x, a3.x); a3.y = fmaf(emr[3][j], v.y, a3.y);
      a3.z = fmaf(emr[3][j], v.z, a3.z); a3.w = fmaf(emr[3][j], v.w, a3.w);
    }
#pragma unroll
    for (int r = 0; r < 4; ++r) {
      float4 ar = (r == 0) ? a0 : (r == 1) ? a1 : (r == 2) ? a2 : a3;
      short4 sv;
      sv.x = bf16s(ar.x);
      sv.y = bf16s(ar.y);
      sv.z = bf16s(ar.z);
      sv.w = bf16s(ar.w);
      *(short4*)&gs[base + (w * 4 + r) * F_ + c0] = sv;
    }
  }
}

// ---------------------------------------------------------------------------
// gemm_h2 (MFMA): h2 = relu(g @ w2bf^T), IN-PLACE on gbuf.
// BM=128, BN=512(full), BK=32; 512 threads (8 waves, 2x4), grid 1024.
// ---------------------------------------------------------------------------
__global__ __launch_bounds__(512, 2) void gemm_h2(
    __hip_bfloat16* __restrict__ gbuf, const __hip_bfloat16* __restrict__ w2bf)
{
  __shared__ __align__(16) short As[128 * 32];  // 8 KB
  __shared__ __align__(16) short Bs[512 * 32];  // 32 KB

  short* gs = (short*)gbuf;
  const short* ws = (const short*)w2bf;

  const int tid = threadIdx.x;
  const long long m0 = (long long)blockIdx.x * 128;
  const int wave8 = tid >> 6, lane = tid & 63;
  const int wr = wave8 >> 2, wcol = wave8 & 3;
  const int rowU = tid >> 2, chkU = (tid & 3) * 8;
  const int mrow = lane & 15, kq = (lane >> 4) * 8;

  f32x4_t acc[4][8];
#pragma unroll
  for (int i = 0; i < 4; ++i)
#pragma unroll
    for (int j = 0; j < 8; ++j) acc[i][j] = (f32x4_t){0.f, 0.f, 0.f, 0.f};

  for (int kc = 0; kc < F_; kc += 32) {
    gload16(gs + (m0 + rowU) * F_ + kc + chkU, As + rowU * 32 + chkU);
#pragma unroll
    for (int it = 0; it < 4; ++it)
      gload16(ws + (it * 128 + rowU) * F_ + kc + chkU, Bs + (it * 128 + rowU) * 32 + chkU);
    __syncthreads();

    bf16x8_t af[4], bfr[8];
#pragma unroll
    for (int i = 0; i < 4; ++i)
      af[i] = *(const bf16x8_t*)&As[((wr << 6) + i * 16 + mrow) * 32 + kq];
#pragma unroll
    for (int j = 0; j < 8; ++j)
      bfr[j] = *(const bf16x8_t*)&Bs[((wcol << 7) + j * 16 + mrow) * 32 + kq];

#pragma unroll
    for (int i = 0; i < 4; ++i)
#pragma unroll
      for (int j = 0; j < 8; ++j)
        acc[i][j] = __builtin_amdgcn_mfma_f32_16x16x32_bf16(af[i], bfr[j], acc[i][j], 0, 0, 0);
    __syncthreads();
  }

  const int rbase = (lane >> 4) << 2;
#pragma unroll
  for (int i = 0; i < 4; ++i)
#pragma unroll
    for (int j = 0; j < 8; ++j)
#pragma unroll
      for (int r = 0; r < 4; ++r) {
        int row = (wr << 6) + i * 16 + rbase + r;
        int col = (wcol << 7) + j * 16 + mrow;
        float v = fmaxf(acc[i][j][r], 0.f);
        gs[(m0 + row) * F_ + col] = bf16s(v);
      }
}

// ---------------------------------------------------------------------------
// gemm_feat (MFMA): feat = h2[8192x8192] @ wmT^T -> unnormalized out[b][f][t]
// BM=128, BN=128, in-block split-K (512 threads). Grid 256.
// ---------------------------------------------------------------------------
__global__ __launch_bounds__(512, 2) void gemm_feat(
    const __hip_bfloat16* __restrict__ h2g, const __hip_bfloat16* __restrict__ wmTg,
    float* __restrict__ out)
{
  __shared__ __align__(16) char smem[33792];
  short* As0 = (short*)smem;
  short* Bs0 = (short*)(smem + 8192);
  short* As1 = (short*)(smem + 16384);
  short* Bs1 = (short*)(smem + 24576);
  float* sM = (float*)smem;                  // merge [64][132]
  float* sT = (float*)smem;                  // transpose [128][65]

  const short* h2s  = (const short*)h2g;
  const short* wmTs = (const short*)wmTg;

  const int tid = threadIdx.x;
  const int bx = blockIdx.x;
  const int mt = bx >> 2, nt = bx & 3;
  const long long m0 = (long long)mt * 128;
  const int n0 = nt * 128;

  const int wave8 = tid >> 6;
  const int half = wave8 >> 2;
  const int wave = wave8 & 3;
  const int lane = tid & 63;
  const int wr = wave >> 1, wc = wave & 1;
  const int mrow = lane & 15;
  const int kq = (lane >> 4) * 8;

  const short* aBase = h2s + m0 * K_TOT;
  const short* bBase = wmTs + (long long)n0 * K_TOT;

  const int rowU = tid >> 2, chkU = (tid & 3) * 8;

  f32x4_t acc[4][4];
#pragma unroll
  for (int i = 0; i < 4; ++i)
#pragma unroll
    for (int j = 0; j < 4; ++j) acc[i][j] = (f32x4_t){0.f, 0.f, 0.f, 0.f};

  short* AsH = half ? As1 : As0;
  short* BsH = half ? Bs1 : Bs0;

  for (int ks = 0; ks < 4096; ks += 32) {
    gload16(aBase + (long long)rowU * K_TOT + ks + chkU,        As0 + rowU * 32 + chkU);
    gload16(bBase + (long long)rowU * K_TOT + ks + chkU,        Bs0 + rowU * 32 + chkU);
    gload16(aBase + (long long)rowU * K_TOT + 4096 + ks + chkU, As1 + rowU * 32 + chkU);
    gload16(bBase + (long long)rowU * K_TOT + 4096 + ks + chkU, Bs1 + rowU * 32 + chkU);
    __syncthreads();

    bf16x8_t af[4], bfr[4];
#pragma unroll
    for (int i = 0; i < 4; ++i)
      af[i] = *(const bf16x8_t*)&AsH[((wr << 6) + i * 16 + mrow) * 32 + kq];
#pragma unroll
    for (int j = 0; j < 4; ++j)
      bfr[j] = *(const bf16x8_t*)&BsH[((wc << 6) + j * 16 + mrow) * 32 + kq];

#pragma unroll
    for (int i = 0; i < 4; ++i)
#pragma unroll
      for (int j = 0; j < 4; ++j)
        acc[i][j] = __builtin_amdgcn_mfma_f32_16x16x32_bf16(af[i], bfr[j], acc[i][j], 0, 0, 0);
    __syncthreads();
  }

  const int rq = (lane >> 4) << 2;
#pragma unroll
  for (int r = 0; r < 2; ++r) {
    if (half == 1 && wr == r) {
#pragma unroll
      for (int i = 0; i < 4; ++i)
#pragma unroll
        for (int j = 0; j < 4; ++j)
#pragma unroll
          for (int rr = 0; rr < 4; ++rr)
            sM[(i * 16 + rq + rr) * 132 + (wc << 6) + j * 16 + mrow] = acc[i][j][rr];
    }
    __syncthreads();
    if (half == 0 && wr == r) {
#pragma unroll
      for (int i = 0; i < 4; ++i)
#pragma unroll
        for (int j = 0; j < 4; ++j)
#pragma unroll
          for (int rr = 0; rr < 4; ++rr)
            acc[i][j][rr] += sM[(i * 16 + rq + rr) * 132 + (wc << 6) + j * 16 + mrow];
    }
    __syncthreads();
  }

  const int b = (int)(m0 >> 11);
  const int t0 = (int)(m0 & 2047);
#pragma unroll
  for (int cch = 0; cch < 2; ++cch) {
    if (half == 0 && wc == cch) {
#pragma unroll
      for (int i = 0; i < 4; ++i)
#pragma unroll
        for (int j = 0; j < 4; ++j)
#pragma unroll
          for (int rr = 0; rr < 4; ++rr)
            sT[((wr << 6) + i * 16 + rq + rr) * 65 + j * 16 + mrow] = acc[i][j][rr];
    }
    __syncthreads();
    long long ob = (long long)b * (F_ * T_) + (long long)(n0 + cch * 64) * T_ + t0;
    for (int idx = tid; idx < 64 * 128; idx += 512) {
      int f = idx >> 7, m = idx & 127;
      out[ob + (long long)f * T_ + m] = sT[m * 65 + f];
    }
    __syncthreads();
  }
}

// ---------------------------------------------------------------------------
// LN in-place on out[b][f][t]: per (b,t) normalize over f
// ---------------------------------------------------------------------------
__global__ __launch_bounds__(256) void ln_inplace(
    float* __restrict__ out, const float* __restrict__ lnw, const float* __restrict__ lnb)
{
  __shared__ float sF[F_ * 17];
  __shared__ float red[512];
  __shared__ float smu[16], srstd[16];

  const int tid = threadIdx.x;
  const int p0 = blockIdx.x << 4;
  const int b = p0 >> 11, t0 = p0 & 2047;
  long long ob = (long long)b * (F_ * T_) + t0;

  for (int idx = tid; idx < F_ * 16; idx += 256) {
    int f = idx >> 4, m = idx & 15;
    sF[f * 17 + m] = out[ob + (long long)f * T_ + m];
  }
  __syncthreads();

  {
    int m = tid & 15, s = tid >> 4;
    float sum = 0.f, sq = 0.f;
    for (int f = s; f < F_; f += 16) {
      float v = sF[f * 17 + m];
      sum += v; sq += v * v;
    }
    red[tid] = sum;
    red[256 + tid] = sq;
  }
  __syncthreads();
  if (tid < 16) {
    float sum = 0.f, sq = 0.f;
#pragma unroll
    for (int s = 0; s < 16; ++s) { sum += red[s * 16 + tid]; sq += red[256 + s * 16 + tid]; }
    float mu = sum * (1.f / F_);
    float var = sq * (1.f / F_) - mu * mu;
    smu[tid] = mu;
    srstd[tid] = rsqrtf(var + LN_EPS);
  }
  __syncthreads();

  for (int idx = tid; idx < F_ * 16; idx += 256) {
    int f = idx >> 4, m = idx & 15;
    float v = (sF[f * 17 + m] - smu[m]) * srstd[m] * lnw[f] + lnb[f];
    out[ob + (long long)f * T_ + m] = v;
  }
}

// ---------------------------------------------------------------------------
extern "C" void kernel_launch(void* const* d_in, const int* in_sizes, int n_in,
                              void* d_out, int out_size, void* d_ws, size_t ws_size,
                              hipStream_t stream)
{
  const float* bbox      = (const float*)d_in[0];
  const int*   cls       = (const int*)d_in[1];
  const float* edge      = (const float*)d_in[2];
  const float* W_lin     = (const float*)d_in[3];
  const float* emb_table = (const float*)d_in[4];
  const float* W1        = (const float*)d_in[5];
  const float* W2        = (const float*)d_in[6];
  const float* Wm        = (const float*)d_in[7];
  const float* lnw       = (const float*)d_in[8];
  const float* lnb       = (const float*)d_in[9];
  float* out = (float*)d_out;

  float* emb1 = (float*)d_ws;
  float* wbox = emb1 + EMB1_N;
  __hip_bfloat16* w2bf = (__hip_bfloat16*)(wbox + WBOX_N);
  __hip_bfloat16* wmT  = w2bf + W2BF_N;
  __hip_bfloat16* gbuf = wmT + WMT_N;   // g, then h2 in-place

  precompute_small<<<(EMB1_N + WBOX_N + W2BF_N) / 256, 256, 0, stream>>>(
      emb_table, W1, W_lin, W2, emb1, wbox, w2bf);
  precompute_wmT<<<F_, 256, 0, stream>>>(Wm, wmT);
  k_h1g<<<B_ * T_, 256, 0, stream>>>(bbox, cls, edge, emb1, wbox, gbuf);
  gemm_h2<<<B_ * T_ * N_ / 128, 512, 0, stream>>>(gbuf, w2bf);
  gemm_feat<<<256, 512, 0, stream>>>(gbuf, wmT, out);
  ln_inplace<<<B_ * T_ / 16, 256, 0, stream>>>(out, lnw, lnb);
}

// Round 9
// 519.997 us; speedup vs baseline: 1.1177x; 1.1177x over previous
//
#include <hip/hip_runtime.h>
#include <hip/hip_bf16.h>

// Problem constants
#define B_  4
#define N_  16
#define T_  2048
#define F_  512
#define NC_ 43
constexpr float LN_EPS = 1e-5f;

constexpr int EMB1_N = NC_ * F_;            // 22016 (fp32)
constexpr int WBOX_N = F_ * 4;              // 2048  (fp32)
constexpr int W2BF_N = F_ * F_;             // 262144 (bf16) native [f][c]
constexpr int WMT_N  = F_ * N_ * F_;        // 4194304 (bf16), wmT[f][k], k=n*F+c
constexpr int K_TOT  = N_ * F_;             // 8192

typedef __bf16 bf16x8_t __attribute__((ext_vector_type(8)));
typedef float  f32x4_t  __attribute__((ext_vector_type(4)));

__device__ __forceinline__ void gload16(const void* g, void* l) {
  __builtin_amdgcn_global_load_lds(
      (const __attribute__((address_space(1))) unsigned int*)g,
      (__attribute__((address_space(3))) unsigned int*)l, 16, 0, 0);
}

__device__ __forceinline__ short bf16s(float x) {
  return (short)__bfloat16_as_ushort(__float2bfloat16(x));
}

// ---------------------------------------------------------------------------
// K0a: emb1[k][f] = sum_c emb_table[k][c] * W1[f][c]
//      wbox[f][q] = sum_c W1[f][F+c] * W_lin[c][q]
//      w2bf[f][c] = bf16(W2[f][c])
// ---------------------------------------------------------------------------
__global__ __launch_bounds__(256) void precompute_small(
    const float* __restrict__ emb_table, const float* __restrict__ W1,
    const float* __restrict__ W_lin, const float* __restrict__ W2,
    float* __restrict__ emb1, float* __restrict__ wbox,
    __hip_bfloat16* __restrict__ w2bf)
{
  int idx = blockIdx.x * 256 + threadIdx.x;
  if (idx < EMB1_N) {
    int k = idx >> 9, f = idx & 511;
    const float4* et = (const float4*)&emb_table[k * F_];
    const float4* w1 = (const float4*)&W1[f * (2 * F_)];
    float s = 0.f;
    for (int c4 = 0; c4 < F_ / 4; ++c4) {
      float4 a = et[c4], b = w1[c4];
      s = fmaf(a.x, b.x, s); s = fmaf(a.y, b.y, s);
      s = fmaf(a.z, b.z, s); s = fmaf(a.w, b.w, s);
    }
    emb1[idx] = s;
  } else if (idx < EMB1_N + WBOX_N) {
    int t2 = idx - EMB1_N;
    int f = t2 >> 2, q = t2 & 3;
    const float4* w1 = (const float4*)&W1[f * (2 * F_) + F_];
    float s = 0.f;
    for (int c4 = 0; c4 < F_ / 4; ++c4) {
      float4 a = w1[c4];
      s = fmaf(a.x, W_lin[(c4 * 4 + 0) * 4 + q], s);
      s = fmaf(a.y, W_lin[(c4 * 4 + 1) * 4 + q], s);
      s = fmaf(a.z, W_lin[(c4 * 4 + 2) * 4 + q], s);
      s = fmaf(a.w, W_lin[(c4 * 4 + 3) * 4 + q], s);
    }
    wbox[t2] = s;
  } else if (idx < EMB1_N + WBOX_N + W2BF_N) {
    int t3 = idx - (EMB1_N + WBOX_N);
    w2bf[t3] = __float2bfloat16(W2[t3]);
  }
}

// ---------------------------------------------------------------------------
// K0b: wmT[f][k], k=n*F+c  <-  Wm[f][c][n].  (r5, proven)
// ---------------------------------------------------------------------------
__global__ __launch_bounds__(256) void precompute_wmT(
    const float* __restrict__ Wm, __hip_bfloat16* __restrict__ wmT)
{
  __shared__ float tile[16 * 517];  // [n][c], 33 KB
  const int f = blockIdx.x;
  const float* src = Wm + (long long)f * 8192;   // [c][n]: idx = c*16+n
  for (int i = threadIdx.x; i < 8192; i += 256) {
    int c = i >> 4, n = i & 15;
    tile[n * 517 + c] = src[i];
  }
  __syncthreads();
  short* dst = (short*)wmT + (long long)f * 8192;  // [n][c]: o = n*512+c
  for (int i = threadIdx.x; i < 4096; i += 256) {
    int o = i << 1;
    int n = o >> 9, c = o & 511;
    short2 sv;
    sv.x = bf16s(tile[n * 517 + c]);
    sv.y = bf16s(tile[n * 517 + c + 1]);
    *(short2*)&dst[o] = sv;
  }
}

// ---------------------------------------------------------------------------
// k_h1g v2: BLOCK PER PIXEL (proven locality), em-mixes on MFMA.
//   S1: node1[j][f] -> n1T[f][j] bf16 (transposed, stride 20 shorts)
//   mix1 (MFMA 16x16x32, K zero-padded 16->32): h1 = relu(em @ node1) -> h1T
//   mix2: g = em @ h1 -> coalesced short4 global stores
// em fragment zeroed for k>=16 cancels garbage in the other operand.
// Frag layouts (verified in this session's GEMMs):
//   A[m=lane&15][k=(lane>>4)*8+t], B^T[n=lane&15][k=(lane>>4)*8+t],
//   D[row=(lane>>4)*4+r][col=lane&15].
// ---------------------------------------------------------------------------
#define N1ST 20   // row stride (shorts) for n1T/h1T: even (b64-aligned), ~conflict-free
__global__ __launch_bounds__(256) void k_h1g(
    const float* __restrict__ bbox, const int* __restrict__ cls,
    const float* __restrict__ edge, const float* __restrict__ emb1,
    const float* __restrict__ wbox, __hip_bfloat16* __restrict__ g)
{
  __shared__ __align__(16) short em_bf[256];            // em[i][j] bf16
  __shared__ __align__(16) short n1T[F_ * N1ST + 32];   // node1T [f][j]
  __shared__ __align__(16) short h1T[F_ * N1ST + 32];   // h1T    [f][i]
  __shared__ int   cls_s[N_];
  __shared__ float bb_s[N_ * 4];

  const int p = blockIdx.x;
  const int b = p >> 11;
  const int t = p & 2047;
  const int tid = threadIdx.x;

  {
    int i = tid >> 4, j = tid & 15;
    em_bf[tid] = bf16s(edge[(((b * N_ + i) * N_ + j) * T_) + t]);
  }
  if (tid < N_) cls_s[tid] = cls[(b * N_ + tid) * T_ + t];
  if (tid < N_ * 4) {
    int j = tid >> 2, q = tid & 3;
    bb_s[tid] = bbox[(((b * N_ + j) * 4 + q) * T_) + t];
  }
  __syncthreads();

  // S1: node1 -> n1T (bf16, transposed). Gather pattern identical to r4/r7.
  const float4* wb4 = (const float4*)wbox;
  for (int idx = tid; idx < N_ * F_; idx += 256) {
    int j = idx >> 9, f = idx & 511;
    float4 wb = wb4[f];
    float v = emb1[cls_s[j] * F_ + f];
    v = fmaf(bb_s[j * 4 + 0], wb.x, v);
    v = fmaf(bb_s[j * 4 + 1], wb.y, v);
    v = fmaf(bb_s[j * 4 + 2], wb.z, v);
    v = fmaf(bb_s[j * 4 + 3], wb.w, v);
    n1T[f * N1ST + j] = bf16s(v);
  }
  __syncthreads();

  const int lane = tid & 63, wv = tid >> 6;
  const int c = lane & 15;        // column index (n-dim / m-dim per frag)
  const int q = lane >> 4;        // quad index: k = 8q+t (inputs), row = 4q+r (D)

  // em fragment: element [c][8q+t]; ZERO for q>=2 (k 16..31 pad)
  union { bf16x8_t v; short4 s[2]; } ef;
  ef.s[0] = (short4){0, 0, 0, 0};
  ef.s[1] = (short4){0, 0, 0, 0};
  if (q < 2) {
    ef.s[0] = *(const short4*)&em_bf[c * 16 + 8 * q];
    ef.s[1] = *(const short4*)&em_bf[c * 16 + 8 * q + 4];
  }
  const int ko = (q < 2) ? 8 * q : 0;  // clamped addr for q>=2 (garbage; em zero cancels)

  short* gs = (short*)g;
  const long long gbase = (long long)p * (N_ * F_);

#pragma unroll
  for (int tl = 0; tl < 8; ++tl) {
    const int ft = wv * 8 + tl;
    const int row = (ft * 16 + c) * N1ST;

    // mix1: D[i][f_local] = em @ node1  (A=em frag, B=n1T frag)
    union { bf16x8_t v; short4 s[2]; } bf_;
    bf_.s[0] = *(const short4*)&n1T[row + ko];
    bf_.s[1] = *(const short4*)&n1T[row + ko + 4];
    f32x4_t d1 = __builtin_amdgcn_mfma_f32_16x16x32_bf16(
        ef.v, bf_.v, (f32x4_t){0.f, 0.f, 0.f, 0.f}, 0, 0, 0);
    // lane holds h1[i=4q+r][f=ft*16+c]; pack r -> b64 write h1T[f][4q..4q+3]
    short4 hv;
    hv.x = bf16s(fmaxf(d1[0], 0.f));
    hv.y = bf16s(fmaxf(d1[1], 0.f));
    hv.z = bf16s(fmaxf(d1[2], 0.f));
    hv.w = bf16s(fmaxf(d1[3], 0.f));
    *(short4*)&h1T[row + 4 * q] = hv;

    // mix2: D[f_local][i] = h1T-rows @ em  (A=h1T frag, B=em frag)
    // wave-local dependency (same f rows) -> no barrier needed
    union { bf16x8_t v; short4 s[2]; } af_;
    af_.s[0] = *(const short4*)&h1T[row + ko];
    af_.s[1] = *(const short4*)&h1T[row + ko + 4];
    f32x4_t d2 = __builtin_amdgcn_mfma_f32_16x16x32_bf16(
        af_.v, ef.v, (f32x4_t){0.f, 0.f, 0.f, 0.f}, 0, 0, 0);
    // lane holds g[i=c][f=ft*16+4q+r] -> coalesced short4 store
    short4 gv;
    gv.x = bf16s(d2[0]);
    gv.y = bf16s(d2[1]);
    gv.z = bf16s(d2[2]);
    gv.w = bf16s(d2[3]);
    *(short4*)&gs[gbase + c * F_ + ft * 16 + 4 * q] = gv;
  }
}

// ---------------------------------------------------------------------------
// gemm_h2 (MFMA): h2 = relu(g @ w2bf^T), IN-PLACE on gbuf.
// BM=128, BN=512(full), BK=32; 512 threads (8 waves, 2x4), grid 1024.
// ---------------------------------------------------------------------------
__global__ __launch_bounds__(512, 2) void gemm_h2(
    __hip_bfloat16* __restrict__ gbuf, const __hip_bfloat16* __restrict__ w2bf)
{
  __shared__ __align__(16) short As[128 * 32];  // 8 KB
  __shared__ __align__(16) short Bs[512 * 32];  // 32 KB

  short* gs = (short*)gbuf;
  const short* ws = (const short*)w2bf;

  const int tid = threadIdx.x;
  const long long m0 = (long long)blockIdx.x * 128;
  const int wave8 = tid >> 6, lane = tid & 63;
  const int wr = wave8 >> 2, wcol = wave8 & 3;
  const int rowU = tid >> 2, chkU = (tid & 3) * 8;
  const int mrow = lane & 15, kq = (lane >> 4) * 8;

  f32x4_t acc[4][8];
#pragma unroll
  for (int i = 0; i < 4; ++i)
#pragma unroll
    for (int j = 0; j < 8; ++j) acc[i][j] = (f32x4_t){0.f, 0.f, 0.f, 0.f};

  for (int kc = 0; kc < F_; kc += 32) {
    gload16(gs + (m0 + rowU) * F_ + kc + chkU, As + rowU * 32 + chkU);
#pragma unroll
    for (int it = 0; it < 4; ++it)
      gload16(ws + (it * 128 + rowU) * F_ + kc + chkU, Bs + (it * 128 + rowU) * 32 + chkU);
    __syncthreads();

    bf16x8_t af[4], bfr[8];
#pragma unroll
    for (int i = 0; i < 4; ++i)
      af[i] = *(const bf16x8_t*)&As[((wr << 6) + i * 16 + mrow) * 32 + kq];
#pragma unroll
    for (int j = 0; j < 8; ++j)
      bfr[j] = *(const bf16x8_t*)&Bs[((wcol << 7) + j * 16 + mrow) * 32 + kq];

#pragma unroll
    for (int i = 0; i < 4; ++i)
#pragma unroll
      for (int j = 0; j < 8; ++j)
        acc[i][j] = __builtin_amdgcn_mfma_f32_16x16x32_bf16(af[i], bfr[j], acc[i][j], 0, 0, 0);
    __syncthreads();
  }

  const int rbase = (lane >> 4) << 2;
#pragma unroll
  for (int i = 0; i < 4; ++i)
#pragma unroll
    for (int j = 0; j < 8; ++j)
#pragma unroll
      for (int r = 0; r < 4; ++r) {
        int row = (wr << 6) + i * 16 + rbase + r;
        int col = (wcol << 7) + j * 16 + mrow;
        float v = fmaxf(acc[i][j][r], 0.f);
        gs[(m0 + row) * F_ + col] = bf16s(v);
      }
}

// ---------------------------------------------------------------------------
// gemm_feat (MFMA): feat = h2[8192x8192] @ wmT^T -> unnormalized out[b][f][t]
// BM=128, BN=128, in-block split-K (512 threads). Grid 256.
// ---------------------------------------------------------------------------
__global__ __launch_bounds__(512, 2) void gemm_feat(
    const __hip_bfloat16* __restrict__ h2g, const __hip_bfloat16* __restrict__ wmTg,
    float* __restrict__ out)
{
  __shared__ __align__(16) char smem[33792];
  short* As0 = (short*)smem;
  short* Bs0 = (short*)(smem + 8192);
  short* As1 = (short*)(smem + 16384);
  short* Bs1 = (short*)(smem + 24576);
  float* sM = (float*)smem;                  // merge [64][132]
  float* sT = (float*)smem;                  // transpose [128][65]

  const short* h2s  = (const short*)h2g;
  const short* wmTs = (const short*)wmTg;

  const int tid = threadIdx.x;
  const int bx = blockIdx.x;
  const int mt = bx >> 2, nt = bx & 3;
  const long long m0 = (long long)mt * 128;
  const int n0 = nt * 128;

  const int wave8 = tid >> 6;
  const int half = wave8 >> 2;
  const int wave = wave8 & 3;
  const int lane = tid & 63;
  const int wr = wave >> 1, wc = wave & 1;
  const int mrow = lane & 15;
  const int kq = (lane >> 4) * 8;

  const short* aBase = h2s + m0 * K_TOT;
  const short* bBase = wmTs + (long long)n0 * K_TOT;

  const int rowU = tid >> 2, chkU = (tid & 3) * 8;

  f32x4_t acc[4][4];
#pragma unroll
  for (int i = 0; i < 4; ++i)
#pragma unroll
    for (int j = 0; j < 4; ++j) acc[i][j] = (f32x4_t){0.f, 0.f, 0.f, 0.f};

  short* AsH = half ? As1 : As0;
  short* BsH = half ? Bs1 : Bs0;

  for (int ks = 0; ks < 4096; ks += 32) {
    gload16(aBase + (long long)rowU * K_TOT + ks + chkU,        As0 + rowU * 32 + chkU);
    gload16(bBase + (long long)rowU * K_TOT + ks + chkU,        Bs0 + rowU * 32 + chkU);
    gload16(aBase + (long long)rowU * K_TOT + 4096 + ks + chkU, As1 + rowU * 32 + chkU);
    gload16(bBase + (long long)rowU * K_TOT + 4096 + ks + chkU, Bs1 + rowU * 32 + chkU);
    __syncthreads();

    bf16x8_t af[4], bfr[4];
#pragma unroll
    for (int i = 0; i < 4; ++i)
      af[i] = *(const bf16x8_t*)&AsH[((wr << 6) + i * 16 + mrow) * 32 + kq];
#pragma unroll
    for (int j = 0; j < 4; ++j)
      bfr[j] = *(const bf16x8_t*)&BsH[((wc << 6) + j * 16 + mrow) * 32 + kq];

#pragma unroll
    for (int i = 0; i < 4; ++i)
#pragma unroll
      for (int j = 0; j < 4; ++j)
        acc[i][j] = __builtin_amdgcn_mfma_f32_16x16x32_bf16(af[i], bfr[j], acc[i][j], 0, 0, 0);
    __syncthreads();
  }

  const int rq = (lane >> 4) << 2;
#pragma unroll
  for (int r = 0; r < 2; ++r) {
    if (half == 1 && wr == r) {
#pragma unroll
      for (int i = 0; i < 4; ++i)
#pragma unroll
        for (int j = 0; j < 4; ++j)
#pragma unroll
          for (int rr = 0; rr < 4; ++rr)
            sM[(i * 16 + rq + rr) * 132 + (wc << 6) + j * 16 + mrow] = acc[i][j][rr];
    }
    __syncthreads();
    if (half == 0 && wr == r) {
#pragma unroll
      for (int i = 0; i < 4; ++i)
#pragma unroll
        for (int j = 0; j < 4; ++j)
#pragma unroll
          for (int rr = 0; rr < 4; ++rr)
            acc[i][j][rr] += sM[(i * 16 + rq + rr) * 132 + (wc << 6) + j * 16 + mrow];
    }
    __syncthreads();
  }

  const int b = (int)(m0 >> 11);
  const int t0 = (int)(m0 & 2047);
#pragma unroll
  for (int cch = 0; cch < 2; ++cch) {
    if (half == 0 && wc == cch) {
#pragma unroll
      for (int i = 0; i < 4; ++i)
#pragma unroll
        for (int j = 0; j < 4; ++j)
#pragma unroll
          for (int rr = 0; rr < 4; ++rr)
            sT[((wr << 6) + i * 16 + rq + rr) * 65 + j * 16 + mrow] = acc[i][j][rr];
    }
    __syncthreads();
    long long ob = (long long)b * (F_ * T_) + (long long)(n0 + cch * 64) * T_ + t0;
    for (int idx = tid; idx < 64 * 128; idx += 512) {
      int f = idx >> 7, m = idx & 127;
      out[ob + (long long)f * T_ + m] = sT[m * 65 + f];
    }
    __syncthreads();
  }
}

// ---------------------------------------------------------------------------
// LN in-place on out[b][f][t]: per (b,t) normalize over f
// ---------------------------------------------------------------------------
__global__ __launch_bounds__(256) void ln_inplace(
    float* __restrict__ out, const float* __restrict__ lnw, const float* __restrict__ lnb)
{
  __shared__ float sF[F_ * 17];
  __shared__ float red[512];
  __shared__ float smu[16], srstd[16];

  const int tid = threadIdx.x;
  const int p0 = blockIdx.x << 4;
  const int b = p0 >> 11, t0 = p0 & 2047;
  long long ob = (long long)b * (F_ * T_) + t0;

  for (int idx = tid; idx < F_ * 16; idx += 256) {
    int f = idx >> 4, m = idx & 15;
    sF[f * 17 + m] = out[ob + (long long)f * T_ + m];
  }
  __syncthreads();

  {
    int m = tid & 15, s = tid >> 4;
    float sum = 0.f, sq = 0.f;
    for (int f = s; f < F_; f += 16) {
      float v = sF[f * 17 + m];
      sum += v; sq += v * v;
    }
    red[tid] = sum;
    red[256 + tid] = sq;
  }
  __syncthreads();
  if (tid < 16) {
    float sum = 0.f, sq = 0.f;
#pragma unroll
    for (int s = 0; s < 16; ++s) { sum += red[s * 16 + tid]; sq += red[256 + s * 16 + tid]; }
    float mu = sum * (1.f / F_);
    float var = sq * (1.f / F_) - mu * mu;
    smu[tid] = mu;
    srstd[tid] = rsqrtf(var + LN_EPS);
  }
  __syncthreads();

  for (int idx = tid; idx < F_ * 16; idx += 256) {
    int f = idx >> 4, m = idx & 15;
    float v = (sF[f * 17 + m] - smu[m]) * srstd[m] * lnw[f] + lnb[f];
    out[ob + (long long)f * T_ + m] = v;
  }
}

// ---------------------------------------------------------------------------
extern "C" void kernel_launch(void* const* d_in, const int* in_sizes, int n_in,
                              void* d_out, int out_size, void* d_ws, size_t ws_size,
                              hipStream_t stream)
{
  const float* bbox      = (const float*)d_in[0];
  const int*   cls       = (const int*)d_in[1];
  const float* edge      = (const float*)d_in[2];
  const float* W_lin     = (const float*)d_in[3];
  const float* emb_table = (const float*)d_in[4];
  const float* W1        = (const float*)d_in[5];
  const float* W2        = (const float*)d_in[6];
  const float* Wm        = (const float*)d_in[7];
  const float* lnw       = (const float*)d_in[8];
  const float* lnb       = (const float*)d_in[9];
  float* out = (float*)d_out;

  float* emb1 = (float*)d_ws;
  float* wbox = emb1 + EMB1_N;
  __hip_bfloat16* w2bf = (__hip_bfloat16*)(wbox + WBOX_N);
  __hip_bfloat16* wmT  = w2bf + W2BF_N;
  __hip_bfloat16* gbuf = wmT + WMT_N;   // g, then h2 in-place

  precompute_small<<<(EMB1_N + WBOX_N + W2BF_N) / 256, 256, 0, stream>>>(
      emb_table, W1, W_lin, W2, emb1, wbox, w2bf);
  precompute_wmT<<<F_, 256, 0, stream>>>(Wm, wmT);
  k_h1g<<<B_ * T_, 256, 0, stream>>>(bbox, cls, edge, emb1, wbox, gbuf);
  gemm_h2<<<B_ * T_ * N_ / 128, 512, 0, stream>>>(gbuf, w2bf);
  gemm_feat<<<256, 512, 0, stream>>>(gbuf, wmT, out);
  ln_inplace<<<B_ * T_ / 16, 256, 0, stream>>>(out, lnw, lnb);
}

// Round 10
// 489.673 us; speedup vs baseline: 1.1869x; 1.0619x over previous
//
#include <hip/hip_runtime.h>
#include <hip/hip_bf16.h>

// Problem constants
#define B_  4
#define N_  16
#define T_  2048
#define F_  512
#define NC_ 43
constexpr float LN_EPS = 1e-5f;

constexpr int EMB1_N = NC_ * F_;            // 22016 (fp32)
constexpr int WBOX_N = F_ * 4;              // 2048  (fp32)
constexpr int W2BF_N = F_ * F_;             // 262144 (bf16) native [f][c]
constexpr int WMT_N  = F_ * N_ * F_;        // 4194304 (bf16), wmT[f][k], k=n*F+c
constexpr int K_TOT  = N_ * F_;             // 8192

typedef __bf16 bf16x8_t __attribute__((ext_vector_type(8)));
typedef float  f32x4_t  __attribute__((ext_vector_type(4)));

__device__ __forceinline__ void gload16(const void* g, void* l) {
  __builtin_amdgcn_global_load_lds(
      (const __attribute__((address_space(1))) unsigned int*)g,
      (__attribute__((address_space(3))) unsigned int*)l, 16, 0, 0);
}

__device__ __forceinline__ short bf16s(float x) {
  return (short)__bfloat16_as_ushort(__float2bfloat16(x));
}

// ---------------------------------------------------------------------------
// K0a: emb1[k][f] = sum_c emb_table[k][c] * W1[f][c]
//      wbox[f][q] = sum_c W1[f][F+c] * W_lin[c][q]
//      w2bf[f][c] = bf16(W2[f][c])
// ---------------------------------------------------------------------------
__global__ __launch_bounds__(256) void precompute_small(
    const float* __restrict__ emb_table, const float* __restrict__ W1,
    const float* __restrict__ W_lin, const float* __restrict__ W2,
    float* __restrict__ emb1, float* __restrict__ wbox,
    __hip_bfloat16* __restrict__ w2bf)
{
  int idx = blockIdx.x * 256 + threadIdx.x;
  if (idx < EMB1_N) {
    int k = idx >> 9, f = idx & 511;
    const float4* et = (const float4*)&emb_table[k * F_];
    const float4* w1 = (const float4*)&W1[f * (2 * F_)];
    float s = 0.f;
    for (int c4 = 0; c4 < F_ / 4; ++c4) {
      float4 a = et[c4], b = w1[c4];
      s = fmaf(a.x, b.x, s); s = fmaf(a.y, b.y, s);
      s = fmaf(a.z, b.z, s); s = fmaf(a.w, b.w, s);
    }
    emb1[idx] = s;
  } else if (idx < EMB1_N + WBOX_N) {
    int t2 = idx - EMB1_N;
    int f = t2 >> 2, q = t2 & 3;
    const float4* w1 = (const float4*)&W1[f * (2 * F_) + F_];
    float s = 0.f;
    for (int c4 = 0; c4 < F_ / 4; ++c4) {
      float4 a = w1[c4];
      s = fmaf(a.x, W_lin[(c4 * 4 + 0) * 4 + q], s);
      s = fmaf(a.y, W_lin[(c4 * 4 + 1) * 4 + q], s);
      s = fmaf(a.z, W_lin[(c4 * 4 + 2) * 4 + q], s);
      s = fmaf(a.w, W_lin[(c4 * 4 + 3) * 4 + q], s);
    }
    wbox[t2] = s;
  } else if (idx < EMB1_N + WBOX_N + W2BF_N) {
    int t3 = idx - (EMB1_N + WBOX_N);
    w2bf[t3] = __float2bfloat16(W2[t3]);
  }
}

// ---------------------------------------------------------------------------
// K0b: wmT[f][k], k=n*F+c  <-  Wm[f][c][n].  (r5, proven)
// ---------------------------------------------------------------------------
__global__ __launch_bounds__(256) void precompute_wmT(
    const float* __restrict__ Wm, __hip_bfloat16* __restrict__ wmT)
{
  __shared__ float tile[16 * 517];  // [n][c], 33 KB
  const int f = blockIdx.x;
  const float* src = Wm + (long long)f * 8192;   // [c][n]: idx = c*16+n
  for (int i = threadIdx.x; i < 8192; i += 256) {
    int c = i >> 4, n = i & 15;
    tile[n * 517 + c] = src[i];
  }
  __syncthreads();
  short* dst = (short*)wmT + (long long)f * 8192;  // [n][c]: o = n*512+c
  for (int i = threadIdx.x; i < 4096; i += 256) {
    int o = i << 1;
    int n = o >> 9, c = o & 511;
    short2 sv;
    sv.x = bf16s(tile[n * 517 + c]);
    sv.y = bf16s(tile[n * 517 + c + 1]);
    *(short2*)&dst[o] = sv;
  }
}

// ---------------------------------------------------------------------------
// k_h1g v2 (r9, proven): BLOCK PER PIXEL, em-mixes on MFMA.
// ---------------------------------------------------------------------------
#define N1ST 20
__global__ __launch_bounds__(256) void k_h1g(
    const float* __restrict__ bbox, const int* __restrict__ cls,
    const float* __restrict__ edge, const float* __restrict__ emb1,
    const float* __restrict__ wbox, __hip_bfloat16* __restrict__ g)
{
  __shared__ __align__(16) short em_bf[256];            // em[i][j] bf16
  __shared__ __align__(16) short n1T[F_ * N1ST + 32];   // node1T [f][j]
  __shared__ __align__(16) short h1T[F_ * N1ST + 32];   // h1T    [f][i]
  __shared__ int   cls_s[N_];
  __shared__ float bb_s[N_ * 4];

  const int p = blockIdx.x;
  const int b = p >> 11;
  const int t = p & 2047;
  const int tid = threadIdx.x;

  {
    int i = tid >> 4, j = tid & 15;
    em_bf[tid] = bf16s(edge[(((b * N_ + i) * N_ + j) * T_) + t]);
  }
  if (tid < N_) cls_s[tid] = cls[(b * N_ + tid) * T_ + t];
  if (tid < N_ * 4) {
    int j = tid >> 2, q = tid & 3;
    bb_s[tid] = bbox[(((b * N_ + j) * 4 + q) * T_) + t];
  }
  __syncthreads();

  const float4* wb4 = (const float4*)wbox;
  for (int idx = tid; idx < N_ * F_; idx += 256) {
    int j = idx >> 9, f = idx & 511;
    float4 wb = wb4[f];
    float v = emb1[cls_s[j] * F_ + f];
    v = fmaf(bb_s[j * 4 + 0], wb.x, v);
    v = fmaf(bb_s[j * 4 + 1], wb.y, v);
    v = fmaf(bb_s[j * 4 + 2], wb.z, v);
    v = fmaf(bb_s[j * 4 + 3], wb.w, v);
    n1T[f * N1ST + j] = bf16s(v);
  }
  __syncthreads();

  const int lane = tid & 63, wv = tid >> 6;
  const int c = lane & 15;
  const int q = lane >> 4;

  union { bf16x8_t v; short4 s[2]; } ef;
  ef.s[0] = (short4){0, 0, 0, 0};
  ef.s[1] = (short4){0, 0, 0, 0};
  if (q < 2) {
    ef.s[0] = *(const short4*)&em_bf[c * 16 + 8 * q];
    ef.s[1] = *(const short4*)&em_bf[c * 16 + 8 * q + 4];
  }
  const int ko = (q < 2) ? 8 * q : 0;

  short* gs = (short*)g;
  const long long gbase = (long long)p * (N_ * F_);

#pragma unroll
  for (int tl = 0; tl < 8; ++tl) {
    const int ft = wv * 8 + tl;
    const int row = (ft * 16 + c) * N1ST;

    union { bf16x8_t v; short4 s[2]; } bf_;
    bf_.s[0] = *(const short4*)&n1T[row + ko];
    bf_.s[1] = *(const short4*)&n1T[row + ko + 4];
    f32x4_t d1 = __builtin_amdgcn_mfma_f32_16x16x32_bf16(
        ef.v, bf_.v, (f32x4_t){0.f, 0.f, 0.f, 0.f}, 0, 0, 0);
    short4 hv;
    hv.x = bf16s(fmaxf(d1[0], 0.f));
    hv.y = bf16s(fmaxf(d1[1], 0.f));
    hv.z = bf16s(fmaxf(d1[2], 0.f));
    hv.w = bf16s(fmaxf(d1[3], 0.f));
    *(short4*)&h1T[row + 4 * q] = hv;

    union { bf16x8_t v; short4 s[2]; } af_;
    af_.s[0] = *(const short4*)&h1T[row + ko];
    af_.s[1] = *(const short4*)&h1T[row + ko + 4];
    f32x4_t d2 = __builtin_amdgcn_mfma_f32_16x16x32_bf16(
        af_.v, ef.v, (f32x4_t){0.f, 0.f, 0.f, 0.f}, 0, 0, 0);
    short4 gv;
    gv.x = bf16s(d2[0]);
    gv.y = bf16s(d2[1]);
    gv.z = bf16s(d2[2]);
    gv.w = bf16s(d2[3]);
    *(short4*)&gs[gbase + c * F_ + ft * 16 + 4 * q] = gv;
  }
}

// ---------------------------------------------------------------------------
// gemm_h2 (MFMA): h2 = relu(g @ w2bf^T), IN-PLACE on gbuf.
// BM=128, BN=512(full), BK=32; 512 threads (8 waves, 2x4), grid 1024.
// ---------------------------------------------------------------------------
__global__ __launch_bounds__(512, 2) void gemm_h2(
    __hip_bfloat16* __restrict__ gbuf, const __hip_bfloat16* __restrict__ w2bf)
{
  __shared__ __align__(16) short As[128 * 32];  // 8 KB
  __shared__ __align__(16) short Bs[512 * 32];  // 32 KB

  short* gs = (short*)gbuf;
  const short* ws = (const short*)w2bf;

  const int tid = threadIdx.x;
  const long long m0 = (long long)blockIdx.x * 128;
  const int wave8 = tid >> 6, lane = tid & 63;
  const int wr = wave8 >> 2, wcol = wave8 & 3;
  const int rowU = tid >> 2, chkU = (tid & 3) * 8;
  const int mrow = lane & 15, kq = (lane >> 4) * 8;

  f32x4_t acc[4][8];
#pragma unroll
  for (int i = 0; i < 4; ++i)
#pragma unroll
    for (int j = 0; j < 8; ++j) acc[i][j] = (f32x4_t){0.f, 0.f, 0.f, 0.f};

  for (int kc = 0; kc < F_; kc += 32) {
    gload16(gs + (m0 + rowU) * F_ + kc + chkU, As + rowU * 32 + chkU);
#pragma unroll
    for (int it = 0; it < 4; ++it)
      gload16(ws + (it * 128 + rowU) * F_ + kc + chkU, Bs + (it * 128 + rowU) * 32 + chkU);
    __syncthreads();

    bf16x8_t af[4], bfr[8];
#pragma unroll
    for (int i = 0; i < 4; ++i)
      af[i] = *(const bf16x8_t*)&As[((wr << 6) + i * 16 + mrow) * 32 + kq];
#pragma unroll
    for (int j = 0; j < 8; ++j)
      bfr[j] = *(const bf16x8_t*)&Bs[((wcol << 7) + j * 16 + mrow) * 32 + kq];

#pragma unroll
    for (int i = 0; i < 4; ++i)
#pragma unroll
      for (int j = 0; j < 8; ++j)
        acc[i][j] = __builtin_amdgcn_mfma_f32_16x16x32_bf16(af[i], bfr[j], acc[i][j], 0, 0, 0);
    __syncthreads();
  }

  const int rbase = (lane >> 4) << 2;
#pragma unroll
  for (int i = 0; i < 4; ++i)
#pragma unroll
    for (int j = 0; j < 8; ++j)
#pragma unroll
      for (int r = 0; r < 4; ++r) {
        int row = (wr << 6) + i * 16 + rbase + r;
        int col = (wcol << 7) + j * 16 + mrow;
        float v = fmaxf(acc[i][j][r], 0.f);
        gs[(m0 + row) * F_ + col] = bf16s(v);
      }
}

// ---------------------------------------------------------------------------
// gemm_feat (MFMA): feat = h2[8192x8192] @ wmT^T -> unnormalized out[b][f][t]
// BM=64, BN=128, in-block split-K2, 512 threads (8 waves: 2 K-halves x 4),
// wave tile 32x64 (acc[2][4]). Grid 512 = 2 blocks/CU -> 4 waves/SIMD
// (r9 measured: grid 256 / 2 waves/SIMD was the occupancy limiter).
// ---------------------------------------------------------------------------
__global__ __launch_bounds__(512, 2) void gemm_feat(
    const __hip_bfloat16* __restrict__ h2g, const __hip_bfloat16* __restrict__ wmTg,
    float* __restrict__ out)
{
  __shared__ __align__(16) char smem[24576];
  short* As0 = (short*)smem;                 // [64][32]  4 KB
  short* Bs0 = (short*)(smem + 4096);        // [128][32] 8 KB
  short* As1 = (short*)(smem + 12288);       // [64][32]
  short* Bs1 = (short*)(smem + 16384);       // [128][32]
  float* sM = (float*)smem;                  // merge [32][132]  (16.9 KB)
  float* sT = (float*)smem;                  // transpose [64][65] (16.6 KB)

  const short* h2s  = (const short*)h2g;
  const short* wmTs = (const short*)wmTg;

  const int tid = threadIdx.x;
  const int bx = blockIdx.x;
  const int mt = bx >> 2, nt = bx & 3;
  const long long m0 = (long long)mt * 64;
  const int n0 = nt * 128;

  const int wave8 = tid >> 6;
  const int half = wave8 >> 2;      // K-half of this wave
  const int wave = wave8 & 3;
  const int lane = tid & 63;
  const int wr = wave >> 1, wc = wave & 1;   // rows wr*32, cols wc*64
  const int mrow = lane & 15;
  const int kq = (lane >> 4) * 8;

  const short* aBase = h2s + m0 * K_TOT;
  const short* bBase = wmTs + (long long)n0 * K_TOT;

  // staging indices
  const int rowB = tid >> 2, chkB = (tid & 3) * 8;       // B: 128 rows, 2 loads/thread
  const int hA = tid >> 8;                               // A: 1 load/thread
  const int rA = (tid & 255) >> 2;
  const int kA = (tid & 3) * 8;
  short* AsA = hA ? As1 : As0;

  f32x4_t acc[2][4];
#pragma unroll
  for (int i = 0; i < 2; ++i)
#pragma unroll
    for (int j = 0; j < 4; ++j) acc[i][j] = (f32x4_t){0.f, 0.f, 0.f, 0.f};

  short* AsH = half ? As1 : As0;
  short* BsH = half ? Bs1 : Bs0;

  for (int ks = 0; ks < 4096; ks += 32) {
    gload16(aBase + (long long)rA * K_TOT + hA * 4096 + ks + kA, AsA + rA * 32 + kA);
    gload16(bBase + (long long)rowB * K_TOT + ks + chkB,        Bs0 + rowB * 32 + chkB);
    gload16(bBase + (long long)rowB * K_TOT + 4096 + ks + chkB, Bs1 + rowB * 32 + chkB);
    __syncthreads();

    bf16x8_t af[2], bfr[4];
#pragma unroll
    for (int i = 0; i < 2; ++i)
      af[i] = *(const bf16x8_t*)&AsH[((wr << 5) + i * 16 + mrow) * 32 + kq];
#pragma unroll
    for (int j = 0; j < 4; ++j)
      bfr[j] = *(const bf16x8_t*)&BsH[((wc << 6) + j * 16 + mrow) * 32 + kq];

#pragma unroll
    for (int i = 0; i < 2; ++i)
#pragma unroll
      for (int j = 0; j < 4; ++j)
        acc[i][j] = __builtin_amdgcn_mfma_f32_16x16x32_bf16(af[i], bfr[j], acc[i][j], 0, 0, 0);
    __syncthreads();
  }

  // merge: half-1 accs into half-0 waves, 2 row-rounds (32 rows each) via sM
  const int rq = (lane >> 4) << 2;
#pragma unroll
  for (int r = 0; r < 2; ++r) {
    if (half == 1 && wr == r) {
#pragma unroll
      for (int i = 0; i < 2; ++i)
#pragma unroll
        for (int j = 0; j < 4; ++j)
#pragma unroll
          for (int rr = 0; rr < 4; ++rr)
            sM[(i * 16 + rq + rr) * 132 + (wc << 6) + j * 16 + mrow] = acc[i][j][rr];
    }
    __syncthreads();
    if (half == 0 && wr == r) {
#pragma unroll
      for (int i = 0; i < 2; ++i)
#pragma unroll
        for (int j = 0; j < 4; ++j)
#pragma unroll
          for (int rr = 0; rr < 4; ++rr)
            acc[i][j][rr] += sM[(i * 16 + rq + rr) * 132 + (wc << 6) + j * 16 + mrow];
    }
    __syncthreads();
  }

  // epilogue: transpose col-chunks of 64 via sT, store unnormalized out[b][f][t]
  const int b = (int)(m0 >> 11);
  const int t0 = (int)(m0 & 2047);
#pragma unroll
  for (int cch = 0; cch < 2; ++cch) {
    if (half == 0 && wc == cch) {
#pragma unroll
      for (int i = 0; i < 2; ++i)
#pragma unroll
        for (int j = 0; j < 4; ++j)
#pragma unroll
          for (int rr = 0; rr < 4; ++rr)
            sT[((wr << 5) + i * 16 + rq + rr) * 65 + j * 16 + mrow] = acc[i][j][rr];
    }
    __syncthreads();
    long long ob = (long long)b * (F_ * T_) + (long long)(n0 + cch * 64) * T_ + t0;
    for (int idx = tid; idx < 64 * 64; idx += 512) {
      int f = idx >> 6, m = idx & 63;
      out[ob + (long long)f * T_ + m] = sT[m * 65 + f];
    }
    __syncthreads();
  }
}

// ---------------------------------------------------------------------------
// LN in-place on out[b][f][t]: per (b,t) normalize over f
// ---------------------------------------------------------------------------
__global__ __launch_bounds__(256) void ln_inplace(
    float* __restrict__ out, const float* __restrict__ lnw, const float* __restrict__ lnb)
{
  __shared__ float sF[F_ * 17];
  __shared__ float red[512];
  __shared__ float smu[16], srstd[16];

  const int tid = threadIdx.x;
  const int p0 = blockIdx.x << 4;
  const int b = p0 >> 11, t0 = p0 & 2047;
  long long ob = (long long)b * (F_ * T_) + t0;

  for (int idx = tid; idx < F_ * 16; idx += 256) {
    int f = idx >> 4, m = idx & 15;
    sF[f * 17 + m] = out[ob + (long long)f * T_ + m];
  }
  __syncthreads();

  {
    int m = tid & 15, s = tid >> 4;
    float sum = 0.f, sq = 0.f;
    for (int f = s; f < F_; f += 16) {
      float v = sF[f * 17 + m];
      sum += v; sq += v * v;
    }
    red[tid] = sum;
    red[256 + tid] = sq;
  }
  __syncthreads();
  if (tid < 16) {
    float sum = 0.f, sq = 0.f;
#pragma unroll
    for (int s = 0; s < 16; ++s) { sum += red[s * 16 + tid]; sq += red[256 + s * 16 + tid]; }
    float mu = sum * (1.f / F_);
    float var = sq * (1.f / F_) - mu * mu;
    smu[tid] = mu;
    srstd[tid] = rsqrtf(var + LN_EPS);
  }
  __syncthreads();

  for (int idx = tid; idx < F_ * 16; idx += 256) {
    int f = idx >> 4, m = idx & 15;
    float v = (sF[f * 17 + m] - smu[m]) * srstd[m] * lnw[f] + lnb[f];
    out[ob + (long long)f * T_ + m] = v;
  }
}

// ---------------------------------------------------------------------------
extern "C" void kernel_launch(void* const* d_in, const int* in_sizes, int n_in,
                              void* d_out, int out_size, void* d_ws, size_t ws_size,
                              hipStream_t stream)
{
  const float* bbox      = (const float*)d_in[0];
  const int*   cls       = (const int*)d_in[1];
  const float* edge      = (const float*)d_in[2];
  const float* W_lin     = (const float*)d_in[3];
  const float* emb_table = (const float*)d_in[4];
  const float* W1        = (const float*)d_in[5];
  const float* W2        = (const float*)d_in[6];
  const float* Wm        = (const float*)d_in[7];
  const float* lnw       = (const float*)d_in[8];
  const float* lnb       = (const float*)d_in[9];
  float* out = (float*)d_out;

  float* emb1 = (float*)d_ws;
  float* wbox = emb1 + EMB1_N;
  __hip_bfloat16* w2bf = (__hip_bfloat16*)(wbox + WBOX_N);
  __hip_bfloat16* wmT  = w2bf + W2BF_N;
  __hip_bfloat16* gbuf = wmT + WMT_N;   // g, then h2 in-place

  precompute_small<<<(EMB1_N + WBOX_N + W2BF_N) / 256, 256, 0, stream>>>(
      emb_table, W1, W_lin, W2, emb1, wbox, w2bf);
  precompute_wmT<<<F_, 256, 0, stream>>>(Wm, wmT);
  k_h1g<<<B_ * T_, 256, 0, stream>>>(bbox, cls, edge, emb1, wbox, gbuf);
  gemm_h2<<<B_ * T_ * N_ / 128, 512, 0, stream>>>(gbuf, w2bf);
  gemm_feat<<<512, 512, 0, stream>>>(gbuf, wmT, out);
  ln_inplace<<<B_ * T_ / 16, 256, 0, stream>>>(out, lnw, lnb);
}

// Round 12
// 445.736 us; speedup vs baseline: 1.3039x; 1.0986x over previous
//
#include <hip/hip_runtime.h>
#include <hip/hip_bf16.h>

// Problem constants
#define B_  4
#define N_  16
#define T_  2048
#define F_  512
#define NC_ 43
constexpr float LN_EPS = 1e-5f;

constexpr int EMB1_N = NC_ * F_;            // 22016 (fp32)
constexpr int WBOX_N = F_ * 4;              // 2048  (fp32)
constexpr int W2BF_N = F_ * F_;             // 262144 (bf16) native [f][c]
constexpr int WMT_N  = F_ * N_ * F_;        // 4194304 (bf16), wmT[f][k], k=n*F+c
constexpr int K_TOT  = N_ * F_;             // 8192

typedef __bf16 bf16x8_t __attribute__((ext_vector_type(8)));
typedef float  f32x4_t  __attribute__((ext_vector_type(4)));

__device__ __forceinline__ void gload16(const void* g, void* l) {
  __builtin_amdgcn_global_load_lds(
      (const __attribute__((address_space(1))) unsigned int*)g,
      (__attribute__((address_space(3))) unsigned int*)l, 16, 0, 0);
}

__device__ __forceinline__ short bf16s(float x) {
  return (short)__bfloat16_as_ushort(__float2bfloat16(x));
}

// ---------------------------------------------------------------------------
// K0a: emb1[k][f] = sum_c emb_table[k][c] * W1[f][c]
//      wbox[f][q] = sum_c W1[f][F+c] * W_lin[c][q]
//      w2bf[f][c] = bf16(W2[f][c])
// ---------------------------------------------------------------------------
__global__ __launch_bounds__(256) void precompute_small(
    const float* __restrict__ emb_table, const float* __restrict__ W1,
    const float* __restrict__ W_lin, const float* __restrict__ W2,
    float* __restrict__ emb1, float* __restrict__ wbox,
    __hip_bfloat16* __restrict__ w2bf)
{
  int idx = blockIdx.x * 256 + threadIdx.x;
  if (idx < EMB1_N) {
    int k = idx >> 9, f = idx & 511;
    const float4* et = (const float4*)&emb_table[k * F_];
    const float4* w1 = (const float4*)&W1[f * (2 * F_)];
    float s = 0.f;
    for (int c4 = 0; c4 < F_ / 4; ++c4) {
      float4 a = et[c4], b = w1[c4];
      s = fmaf(a.x, b.x, s); s = fmaf(a.y, b.y, s);
      s = fmaf(a.z, b.z, s); s = fmaf(a.w, b.w, s);
    }
    emb1[idx] = s;
  } else if (idx < EMB1_N + WBOX_N) {
    int t2 = idx - EMB1_N;
    int f = t2 >> 2, q = t2 & 3;
    const float4* w1 = (const float4*)&W1[f * (2 * F_) + F_];
    float s = 0.f;
    for (int c4 = 0; c4 < F_ / 4; ++c4) {
      float4 a = w1[c4];
      s = fmaf(a.x, W_lin[(c4 * 4 + 0) * 4 + q], s);
      s = fmaf(a.y, W_lin[(c4 * 4 + 1) * 4 + q], s);
      s = fmaf(a.z, W_lin[(c4 * 4 + 2) * 4 + q], s);
      s = fmaf(a.w, W_lin[(c4 * 4 + 3) * 4 + q], s);
    }
    wbox[t2] = s;
  } else if (idx < EMB1_N + WBOX_N + W2BF_N) {
    int t3 = idx - (EMB1_N + WBOX_N);
    w2bf[t3] = __float2bfloat16(W2[t3]);
  }
}

// ---------------------------------------------------------------------------
// K0b: wmT[f][k], k=n*F+c  <-  Wm[f][c][n].  (r5, proven)
// ---------------------------------------------------------------------------
__global__ __launch_bounds__(256) void precompute_wmT(
    const float* __restrict__ Wm, __hip_bfloat16* __restrict__ wmT)
{
  __shared__ float tile[16 * 517];  // [n][c], 33 KB
  const int f = blockIdx.x;
  const float* src = Wm + (long long)f * 8192;   // [c][n]: idx = c*16+n
  for (int i = threadIdx.x; i < 8192; i += 256) {
    int c = i >> 4, n = i & 15;
    tile[n * 517 + c] = src[i];
  }
  __syncthreads();
  short* dst = (short*)wmT + (long long)f * 8192;  // [n][c]: o = n*512+c
  for (int i = threadIdx.x; i < 4096; i += 256) {
    int o = i << 1;
    int n = o >> 9, c = o & 511;
    short2 sv;
    sv.x = bf16s(tile[n * 517 + c]);
    sv.y = bf16s(tile[n * 517 + c + 1]);
    *(short2*)&dst[o] = sv;
  }
}

// ---------------------------------------------------------------------------
// k_h1g v2 (r9, proven): BLOCK PER PIXEL, em-mixes on MFMA.
// ---------------------------------------------------------------------------
#define N1ST 20
__global__ __launch_bounds__(256) void k_h1g(
    const float* __restrict__ bbox, const int* __restrict__ cls,
    const float* __restrict__ edge, const float* __restrict__ emb1,
    const float* __restrict__ wbox, __hip_bfloat16* __restrict__ g)
{
  __shared__ __align__(16) short em_bf[256];            // em[i][j] bf16
  __shared__ __align__(16) short n1T[F_ * N1ST + 32];   // node1T [f][j]
  __shared__ __align__(16) short h1T[F_ * N1ST + 32];   // h1T    [f][i]
  __shared__ int   cls_s[N_];
  __shared__ float bb_s[N_ * 4];

  const int p = blockIdx.x;
  const int b = p >> 11;
  const int t = p & 2047;
  const int tid = threadIdx.x;

  {
    int i = tid >> 4, j = tid & 15;
    em_bf[tid] = bf16s(edge[(((b * N_ + i) * N_ + j) * T_) + t]);
  }
  if (tid < N_) cls_s[tid] = cls[(b * N_ + tid) * T_ + t];
  if (tid < N_ * 4) {
    int j = tid >> 2, q = tid & 3;
    bb_s[tid] = bbox[(((b * N_ + j) * 4 + q) * T_) + t];
  }
  __syncthreads();

  const float4* wb4 = (const float4*)wbox;
  for (int idx = tid; idx < N_ * F_; idx += 256) {
    int j = idx >> 9, f = idx & 511;
    float4 wb = wb4[f];
    float v = emb1[cls_s[j] * F_ + f];
    v = fmaf(bb_s[j * 4 + 0], wb.x, v);
    v = fmaf(bb_s[j * 4 + 1], wb.y, v);
    v = fmaf(bb_s[j * 4 + 2], wb.z, v);
    v = fmaf(bb_s[j * 4 + 3], wb.w, v);
    n1T[f * N1ST + j] = bf16s(v);
  }
  __syncthreads();

  const int lane = tid & 63, wv = tid >> 6;
  const int c = lane & 15;
  const int q = lane >> 4;

  union { bf16x8_t v; short4 s[2]; } ef;
  ef.s[0] = (short4){0, 0, 0, 0};
  ef.s[1] = (short4){0, 0, 0, 0};
  if (q < 2) {
    ef.s[0] = *(const short4*)&em_bf[c * 16 + 8 * q];
    ef.s[1] = *(const short4*)&em_bf[c * 16 + 8 * q + 4];
  }
  const int ko = (q < 2) ? 8 * q : 0;

  short* gs = (short*)g;
  const long long gbase = (long long)p * (N_ * F_);

#pragma unroll
  for (int tl = 0; tl < 8; ++tl) {
    const int ft = wv * 8 + tl;
    const int row = (ft * 16 + c) * N1ST;

    union { bf16x8_t v; short4 s[2]; } bf_;
    bf_.s[0] = *(const short4*)&n1T[row + ko];
    bf_.s[1] = *(const short4*)&n1T[row + ko + 4];
    f32x4_t d1 = __builtin_amdgcn_mfma_f32_16x16x32_bf16(
        ef.v, bf_.v, (f32x4_t){0.f, 0.f, 0.f, 0.f}, 0, 0, 0);
    short4 hv;
    hv.x = bf16s(fmaxf(d1[0], 0.f));
    hv.y = bf16s(fmaxf(d1[1], 0.f));
    hv.z = bf16s(fmaxf(d1[2], 0.f));
    hv.w = bf16s(fmaxf(d1[3], 0.f));
    *(short4*)&h1T[row + 4 * q] = hv;

    union { bf16x8_t v; short4 s[2]; } af_;
    af_.s[0] = *(const short4*)&h1T[row + ko];
    af_.s[1] = *(const short4*)&h1T[row + ko + 4];
    f32x4_t d2 = __builtin_amdgcn_mfma_f32_16x16x32_bf16(
        af_.v, ef.v, (f32x4_t){0.f, 0.f, 0.f, 0.f}, 0, 0, 0);
    short4 gv;
    gv.x = bf16s(d2[0]);
    gv.y = bf16s(d2[1]);
    gv.z = bf16s(d2[2]);
    gv.w = bf16s(d2[3]);
    *(short4*)&gs[gbase + c * F_ + ft * 16 + 4 * q] = gv;
  }
}

// ---------------------------------------------------------------------------
// gemm_h2 (MFMA): h2 = relu(g @ w2bf^T), IN-PLACE on gbuf.
// BM=128, BN=512(full), BK=32; 512 threads (8 waves, 2x4), grid 1024.
// ---------------------------------------------------------------------------
__global__ __launch_bounds__(512, 2) void gemm_h2(
    __hip_bfloat16* __restrict__ gbuf, const __hip_bfloat16* __restrict__ w2bf)
{
  __shared__ __align__(16) short As[128 * 32];  // 8 KB
  __shared__ __align__(16) short Bs[512 * 32];  // 32 KB

  short* gs = (short*)gbuf;
  const short* ws = (const short*)w2bf;

  const int tid = threadIdx.x;
  const long long m0 = (long long)blockIdx.x * 128;
  const int wave8 = tid >> 6, lane = tid & 63;
  const int wr = wave8 >> 2, wcol = wave8 & 3;
  const int rowU = tid >> 2, chkU = (tid & 3) * 8;
  const int mrow = lane & 15, kq = (lane >> 4) * 8;

  f32x4_t acc[4][8];
#pragma unroll
  for (int i = 0; i < 4; ++i)
#pragma unroll
    for (int j = 0; j < 8; ++j) acc[i][j] = (f32x4_t){0.f, 0.f, 0.f, 0.f};

  for (int kc = 0; kc < F_; kc += 32) {
    gload16(gs + (m0 + rowU) * F_ + kc + chkU, As + rowU * 32 + chkU);
#pragma unroll
    for (int it = 0; it < 4; ++it)
      gload16(ws + (it * 128 + rowU) * F_ + kc + chkU, Bs + (it * 128 + rowU) * 32 + chkU);
    __syncthreads();

    bf16x8_t af[4], bfr[8];
#pragma unroll
    for (int i = 0; i < 4; ++i)
      af[i] = *(const bf16x8_t*)&As[((wr << 6) + i * 16 + mrow) * 32 + kq];
#pragma unroll
    for (int j = 0; j < 8; ++j)
      bfr[j] = *(const bf16x8_t*)&Bs[((wcol << 7) + j * 16 + mrow) * 32 + kq];

#pragma unroll
    for (int i = 0; i < 4; ++i)
#pragma unroll
      for (int j = 0; j < 8; ++j)
        acc[i][j] = __builtin_amdgcn_mfma_f32_16x16x32_bf16(af[i], bfr[j], acc[i][j], 0, 0, 0);
    __syncthreads();
  }

  const int rbase = (lane >> 4) << 2;
#pragma unroll
  for (int i = 0; i < 4; ++i)
#pragma unroll
    for (int j = 0; j < 8; ++j)
#pragma unroll
      for (int r = 0; r < 4; ++r) {
        int row = (wr << 6) + i * 16 + rbase + r;
        int col = (wcol << 7) + j * 16 + mrow;
        float v = fmaxf(acc[i][j][r], 0.f);
        gs[(m0 + row) * F_ + col] = bf16s(v);
      }
}

// ---------------------------------------------------------------------------
// gemm_feat (MFMA): feat = h2[8192x8192] @ wmT^T -> unnormalized out[b][f][t]
// BM=64, BN=128, in-block split-K2, 512 threads, wave tile 32x64.
// v3: (a) two BK=32 chunks staged per barrier (64 barriers, not 128);
//     (b) XCD-aware decode mt=bx&127, nt=bx>>7: the 4 nt-blocks of one mt
//         share bx%8 -> same XCD -> A rows hit that XCD's L2 once.
// LDS pointers computed at use sites (static pointer-table init doesn't
// compile for addrspace(3) on gfx950).
// ---------------------------------------------------------------------------
__global__ __launch_bounds__(512, 2) void gemm_feat(
    const __hip_bfloat16* __restrict__ h2g, const __hip_bfloat16* __restrict__ wmTg,
    float* __restrict__ out)
{
  __shared__ __align__(16) char smem[49152];
  // As[h][s] = smem + h*8192 + s*4096 (4 KB each)
  // Bs[h][s] = smem + 16384 + (h*2+s)*8192 (8 KB each)
  float* sM = (float*)smem;                  // merge [32][132]  (16.9 KB)
  float* sT = (float*)smem;                  // transpose [64][65] (16.6 KB)

  const short* h2s  = (const short*)h2g;
  const short* wmTs = (const short*)wmTg;

  const int tid = threadIdx.x;
  const int bx = blockIdx.x;
  const int mt = bx & 127, nt = bx >> 7;     // XCD-aware: same mt -> same bx%8
  const long long m0 = (long long)mt * 64;
  const int n0 = nt * 128;

  const int wave8 = tid >> 6;
  const int half = wave8 >> 2;      // K-half of this wave
  const int wave = wave8 & 3;
  const int lane = tid & 63;
  const int wr = wave >> 1, wc = wave & 1;   // rows wr*32, cols wc*64
  const int mrow = lane & 15;
  const int kq = (lane >> 4) * 8;

  const short* aBase = h2s + m0 * K_TOT;
  const short* bBase = wmTs + (long long)n0 * K_TOT;

  // staging indices
  const int rowB = tid >> 2, chkB = (tid & 3) * 8;       // B: 128 rows
  const int hA = tid >> 8;                               // A: half this thread stages
  const int rA = (tid & 255) >> 2;
  const int kA = (tid & 3) * 8;

  f32x4_t acc[2][4];
#pragma unroll
  for (int i = 0; i < 2; ++i)
#pragma unroll
    for (int j = 0; j < 4; ++j) acc[i][j] = (f32x4_t){0.f, 0.f, 0.f, 0.f};

  for (int ks = 0; ks < 4096; ks += 64) {
#pragma unroll
    for (int s = 0; s < 2; ++s)
      gload16(aBase + (long long)rA * K_TOT + hA * 4096 + ks + s * 32 + kA,
              (short*)(smem + hA * 8192 + s * 4096) + rA * 32 + kA);
#pragma unroll
    for (int h = 0; h < 2; ++h)
#pragma unroll
      for (int s = 0; s < 2; ++s)
        gload16(bBase + (long long)rowB * K_TOT + h * 4096 + ks + s * 32 + chkB,
                (short*)(smem + 16384 + (h * 2 + s) * 8192) + rowB * 32 + chkB);
    __syncthreads();

#pragma unroll
    for (int s = 0; s < 2; ++s) {
      const short* AsH = (const short*)(smem + half * 8192 + s * 4096);
      const short* BsH = (const short*)(smem + 16384 + (half * 2 + s) * 8192);
      bf16x8_t af[2], bfr[4];
#pragma unroll
      for (int i = 0; i < 2; ++i)
        af[i] = *(const bf16x8_t*)&AsH[((wr << 5) + i * 16 + mrow) * 32 + kq];
#pragma unroll
      for (int j = 0; j < 4; ++j)
        bfr[j] = *(const bf16x8_t*)&BsH[((wc << 6) + j * 16 + mrow) * 32 + kq];
#pragma unroll
      for (int i = 0; i < 2; ++i)
#pragma unroll
        for (int j = 0; j < 4; ++j)
          acc[i][j] = __builtin_amdgcn_mfma_f32_16x16x32_bf16(af[i], bfr[j], acc[i][j], 0, 0, 0);
    }
    __syncthreads();
  }

  // merge: half-1 accs into half-0 waves, 2 row-rounds (32 rows each) via sM
  const int rq = (lane >> 4) << 2;
#pragma unroll
  for (int r = 0; r < 2; ++r) {
    if (half == 1 && wr == r) {
#pragma unroll
      for (int i = 0; i < 2; ++i)
#pragma unroll
        for (int j = 0; j < 4; ++j)
#pragma unroll
          for (int rr = 0; rr < 4; ++rr)
            sM[(i * 16 + rq + rr) * 132 + (wc << 6) + j * 16 + mrow] = acc[i][j][rr];
    }
    __syncthreads();
    if (half == 0 && wr == r) {
#pragma unroll
      for (int i = 0; i < 2; ++i)
#pragma unroll
        for (int j = 0; j < 4; ++j)
#pragma unroll
          for (int rr = 0; rr < 4; ++rr)
            acc[i][j][rr] += sM[(i * 16 + rq + rr) * 132 + (wc << 6) + j * 16 + mrow];
    }
    __syncthreads();
  }

  // epilogue: transpose col-chunks of 64 via sT, store unnormalized out[b][f][t]
  const int b = (int)(m0 >> 11);
  const int t0 = (int)(m0 & 2047);
#pragma unroll
  for (int cch = 0; cch < 2; ++cch) {
    if (half == 0 && wc == cch) {
#pragma unroll
      for (int i = 0; i < 2; ++i)
#pragma unroll
        for (int j = 0; j < 4; ++j)
#pragma unroll
          for (int rr = 0; rr < 4; ++rr)
            sT[((wr << 5) + i * 16 + rq + rr) * 65 + j * 16 + mrow] = acc[i][j][rr];
    }
    __syncthreads();
    long long ob = (long long)b * (F_ * T_) + (long long)(n0 + cch * 64) * T_ + t0;
    for (int idx = tid; idx < 64 * 64; idx += 512) {
      int f = idx >> 6, m = idx & 63;
      out[ob + (long long)f * T_ + m] = sT[m * 65 + f];
    }
    __syncthreads();
  }
}

// ---------------------------------------------------------------------------
// LN in-place on out[b][f][t]: per (b,t) normalize over f
// ---------------------------------------------------------------------------
__global__ __launch_bounds__(256) void ln_inplace(
    float* __restrict__ out, const float* __restrict__ lnw, const float* __restrict__ lnb)
{
  __shared__ float sF[F_ * 17];
  __shared__ float red[512];
  __shared__ float smu[16], srstd[16];

  const int tid = threadIdx.x;
  const int p0 = blockIdx.x << 4;
  const int b = p0 >> 11, t0 = p0 & 2047;
  long long ob = (long long)b * (F_ * T_) + t0;

  for (int idx = tid; idx < F_ * 16; idx += 256) {
    int f = idx >> 4, m = idx & 15;
    sF[f * 17 + m] = out[ob + (long long)f * T_ + m];
  }
  __syncthreads();

  {
    int m = tid & 15, s = tid >> 4;
    float sum = 0.f, sq = 0.f;
    for (int f = s; f < F_; f += 16) {
      float v = sF[f * 17 + m];
      sum += v; sq += v * v;
    }
    red[tid] = sum;
    red[256 + tid] = sq;
  }
  __syncthreads();
  if (tid < 16) {
    float sum = 0.f, sq = 0.f;
#pragma unroll
    for (int s = 0; s < 16; ++s) { sum += red[s * 16 + tid]; sq += red[256 + s * 16 + tid]; }
    float mu = sum * (1.f / F_);
    float var = sq * (1.f / F_) - mu * mu;
    smu[tid] = mu;
    srstd[tid] = rsqrtf(var + LN_EPS);
  }
  __syncthreads();

  for (int idx = tid; idx < F_ * 16; idx += 256) {
    int f = idx >> 4, m = idx & 15;
    float v = (sF[f * 17 + m] - smu[m]) * srstd[m] * lnw[f] + lnb[f];
    out[ob + (long long)f * T_ + m] = v;
  }
}

// ---------------------------------------------------------------------------
extern "C" void kernel_launch(void* const* d_in, const int* in_sizes, int n_in,
                              void* d_out, int out_size, void* d_ws, size_t ws_size,
                              hipStream_t stream)
{
  const float* bbox      = (const float*)d_in[0];
  const int*   cls       = (const int*)d_in[1];
  const float* edge      = (const float*)d_in[2];
  const float* W_lin     = (const float*)d_in[3];
  const float* emb_table = (const float*)d_in[4];
  const float* W1        = (const float*)d_in[5];
  const float* W2        = (const float*)d_in[6];
  const float* Wm        = (const float*)d_in[7];
  const float* lnw       = (const float*)d_in[8];
  const float* lnb       = (const float*)d_in[9];
  float* out = (float*)d_out;

  float* emb1 = (float*)d_ws;
  float* wbox = emb1 + EMB1_N;
  __hip_bfloat16* w2bf = (__hip_bfloat16*)(wbox + WBOX_N);
  __hip_bfloat16* wmT  = w2bf + W2BF_N;
  __hip_bfloat16* gbuf = wmT + WMT_N;   // g, then h2 in-place

  precompute_small<<<(EMB1_N + WBOX_N + W2BF_N) / 256, 256, 0, stream>>>(
      emb_table, W1, W_lin, W2, emb1, wbox, w2bf);
  precompute_wmT<<<F_, 256, 0, stream>>>(Wm, wmT);
  k_h1g<<<B_ * T_, 256, 0, stream>>>(bbox, cls, edge, emb1, wbox, gbuf);
  gemm_h2<<<B_ * T_ * N_ / 128, 512, 0, stream>>>(gbuf, w2bf);
  gemm_feat<<<512, 512, 0, stream>>>(gbuf, wmT, out);
  ln_inplace<<<B_ * T_ / 16, 256, 0, stream>>>(out, lnw, lnb);
}